// Round 21
// baseline (138.171 us; speedup 1.0000x reference)
//
#include <hip/hip_runtime.h>
#include <math.h>

#define NROWS 32768
#define CDIM  512
#define G_    2
#define V_    320
#define NCOLS 640
#define DCODE 128
#define NSLOT 64
#define BMR   32   // rows per block (R17 config — best at 95us)

typedef short bf16x8 __attribute__((ext_vector_type(8)));
typedef float f32x4  __attribute__((ext_vector_type(4)));
typedef int   i32x4  __attribute__((ext_vector_type(4)));

__device__ __forceinline__ short f2bf(float f) {
    union { float f; unsigned u; } v; v.f = f;
    unsigned r = v.u + 0x7FFFu + ((v.u >> 16) & 1u);   // RTNE
    return (short)(r >> 16);
}
// non-temporal loads: no L1 allocation -> streamed-once data (H, gumbel) stops
// evicting the W lines that all co-resident blocks share (R18 post-mortem:
// per-CU line-fill throughput cap; mixed streams cross-evict).
__device__ __forceinline__ bf16x8 ldnt_bf(const short* p) {
    i32x4 v = __builtin_nontemporal_load((const i32x4*)p);
    union { i32x4 i; bf16x8 b; } u; u.i = v; return u.b;
}
__device__ __forceinline__ f32x4 ldnt_f4(const float* p) {
    return __builtin_nontemporal_load((const f32x4*)p);
}
__device__ __forceinline__ void stnt_f4(float* p, f32x4 v) {
    __builtin_nontemporal_store(v, (f32x4*)p);
}

// W [512][640] f32 -> wpk fragment-packed bf16 (640 KB).
// frag gid = ((g*16+ts)*20 + tt16)*64 + kq*16 + l15, elem e = w[ts*32+kq*8+e][g*320+tt16*16+l15]
__global__ __launch_bounds__(256) void wprep(const float* __restrict__ w,
                                             short* __restrict__ wpk) {
    int gid = blockIdx.x * 256 + threadIdx.x;       // 40960 fragments
    int l15 = gid & 15, kq = (gid >> 4) & 3;
    int rem = gid >> 6;
    int tt16 = rem % 20; rem /= 20;
    int ts = rem & 15, g = rem >> 4;
    int n  = g * V_ + tt16 * 16 + l15;
    int k0 = ts * 32 + kq * 8;
    bf16x8 o;
    #pragma unroll
    for (int e = 0; e < 8; ++e) o[e] = f2bf(w[(size_t)(k0 + e) * NCOLS + n]);
    *(bf16x8*)&wpk[(size_t)gid * 8] = o;
}

// hidden [32768][512] f32 -> hpk fragment-packed bf16 (33.5 MB).
// shorts index (rb,ts,mf,lane,e) = (((rb*16+ts)*2+mf)*64 + lane)*8 + e
//   = bf16(hidden[rb*32 + mf*16 + (lane&15)][ts*32 + (lane>>4)*8 + e])
__global__ __launch_bounds__(256) void hprep(const float* __restrict__ hidden,
                                             short* __restrict__ hpk) {
    int gid = blockIdx.x * 256 + threadIdx.x;       // 2,097,152
    int lane = gid & 63;
    int mf   = (gid >> 6) & 1;
    int ts   = (gid >> 7) & 15;
    int rb   = gid >> 11;
    int row  = rb * BMR + mf * 16 + (lane & 15);
    int k0   = ts * 32 + (lane >> 4) * 8;
    const float* src = hidden + (size_t)row * CDIM + k0;
    float4 a = *(const float4*)src;
    float4 b = *(const float4*)(src + 4);
    bf16x8 o;
    o[0]=f2bf(a.x); o[1]=f2bf(a.y); o[2]=f2bf(a.z); o[3]=f2bf(a.w);
    o[4]=f2bf(b.x); o[5]=f2bf(b.y); o[6]=f2bf(b.z); o[7]=f2bf(b.w);
    union { bf16x8 b; i32x4 i; } u; u.b = o;
    __builtin_nontemporal_store(u.i, (i32x4*)&hpk[(size_t)gid * 8]);
}

// Block = 32 rows x 640 cols, 512 thr = 8 waves; wave cg owns cols cg*80..+80 (g=cg>>2).
// Swapped MFMA: D[n][m] = mfma(Wfrag, Hfrag). K-loop: wpk cached (shared by all
// blocks -> L1 hits), hpk NON-TEMPORAL (streamed once, no L1 pollution).
__global__ __launch_bounds__(512, 3) void gvq_gemm(
    const short* __restrict__ hpk,       // fragment-packed bf16 hidden
    const float* __restrict__ gumbel_u,  // [65536][320] f32
    const short* __restrict__ wpk,       // fragment-packed bf16 W
    const float* __restrict__ bias,      // [640]
    const float* __restrict__ cv,        // [640][128]
    float* __restrict__ out,             // [32768][256] + perp scalar
    float* __restrict__ gavg)            // [NSLOT][640]
{
    __shared__ float s_psum[G_][4][BMR];
    __shared__ float s_bestv[G_][4][BMR];
    __shared__ int   s_besti[G_][4][BMR];

    const int t    = threadIdx.x;
    const int wave = t >> 6;
    const int lane = t & 63;
    const int l15  = lane & 15;
    const int kq   = lane >> 4;
    const int cg   = wave;               // col group: 80 cols
    const int g    = cg >> 2;
    const int tb   = (cg & 3) * 5;       // tt16 base within group g
    const int rb   = blockIdx.x;
    const int m0   = rb * BMR;

    const short* wbase = wpk + ((size_t)(g * 16) * 20 + tb) * 512 + (size_t)lane * 8;
    const short* hbase = hpk + (size_t)rb * 16384 + (size_t)lane * 8;  // + ts*1024 + mf*512

    f32x4 acc[5][2];                     // [nf][mf]
    #pragma unroll
    for (int nf = 0; nf < 5; ++nf)
        #pragma unroll
        for (int mf = 0; mf < 2; ++mf)
            #pragma unroll
            for (int r = 0; r < 4; ++r) acc[nf][mf][r] = 0.f;

    bf16x8 bw[5], hf0, hf1;
    #pragma unroll
    for (int nf = 0; nf < 5; ++nf) bw[nf] = *(const bf16x8*)(wbase + nf * 512);
    hf0 = ldnt_bf(hbase);
    hf1 = ldnt_bf(hbase + 512);

    #pragma unroll
    for (int ts = 0; ts < 16; ++ts) {
        bf16x8 bn[5], hn0, hn1;
        if (ts < 15) {                   // prefetch ts+1 (W cached, H non-temporal)
            const short* wn = wbase + (ts + 1) * 10240;
            #pragma unroll
            for (int nf = 0; nf < 5; ++nf) bn[nf] = *(const bf16x8*)(wn + nf * 512);
            hn0 = ldnt_bf(hbase + (ts + 1) * 1024);
            hn1 = ldnt_bf(hbase + (ts + 1) * 1024 + 512);
        }
        #pragma unroll
        for (int nf = 0; nf < 5; ++nf)
            acc[nf][0] = __builtin_amdgcn_mfma_f32_16x16x32_bf16(bw[nf], hf0, acc[nf][0], 0, 0, 0);
        #pragma unroll
        for (int nf = 0; nf < 5; ++nf)
            acc[nf][1] = __builtin_amdgcn_mfma_f32_16x16x32_bf16(bw[nf], hf1, acc[nf][1], 0, 0, 0);
        #pragma unroll
        for (int nf = 0; nf < 5; ++nf) bw[nf] = bn[nf];
        hf0 = hn0; hf1 = hn1;
    }

    // ---- epilogue (lane owns rows m0+mf*16+l15, cols g*320+(tb+nf)*16+kq*4+r) ----
    f32x4 bv4[5], u4[2][5];
    #pragma unroll
    for (int nf = 0; nf < 5; ++nf)
        bv4[nf] = *(const f32x4*)&bias[g * V_ + (tb + nf) * 16 + kq * 4];
    #pragma unroll
    for (int mf = 0; mf < 2; ++mf) {
        const float* up = gumbel_u + ((size_t)(m0 + mf * 16 + l15) * G_ + g) * V_;
        #pragma unroll
        for (int nf = 0; nf < 5; ++nf)
            u4[mf][nf] = ldnt_f4(&up[(tb + nf) * 16 + kq * 4]);
    }

    #pragma unroll
    for (int mf = 0; mf < 2; ++mf) {
        float s = 0.f, best = -1e30f; int bi = 0;
        #pragma unroll
        for (int nf = 0; nf < 5; ++nf) {
            #pragma unroll
            for (int r = 0; r < 4; ++r) {
                float z = fminf(acc[nf][mf][r] + bv4[nf][r], 60.f);
                float e = __expf(z);
                acc[nf][mf][r] = e;                        // keep numerator for cp
                s += e;
                float u = u4[mf][nf][r];
                float wv = -__logf(u + 1e-10f) + 1e-10f;
                float ratio = e * __builtin_amdgcn_rcpf(wv);  // argmax(z+gumbel)==argmax e/wv
                const int vi = (tb + nf) * 16 + kq * 4 + r;   // ascending scan -> first-max
                if (ratio > best) { best = ratio; bi = vi; }
            }
        }
        // reduce across kq groups (cols): lanes l15, l15+16, l15+32, l15+48
        #pragma unroll
        for (int o = 16; o <= 32; o <<= 1) {
            s += __shfl_xor(s, o);
            float ov = __shfl_xor(best, o);
            int   oi = __shfl_xor(bi, o);
            if (ov > best || (ov == best && oi < bi)) { best = ov; bi = oi; }
        }
        if (kq == 0) {                       // lanes 0..15
            s_psum[g][cg & 3][mf * 16 + l15]  = s;
            s_bestv[g][cg & 3][mf * 16 + l15] = best;
            s_besti[g][cg & 3][mf * 16 + l15] = bi;
        }
    }
    __syncthreads();

    // ---- cp: per-lane e*inv summed over its 2 rows, fold l15, atomics (1 per col) ----
    float inv[2];
    #pragma unroll
    for (int mf = 0; mf < 2; ++mf) {
        const int rl = mf * 16 + l15;
        inv[mf] = 1.f / (s_psum[g][0][rl] + s_psum[g][1][rl] +
                         s_psum[g][2][rl] + s_psum[g][3][rl]);
    }
    float cpl[5][4];
    #pragma unroll
    for (int nf = 0; nf < 5; ++nf)
        #pragma unroll
        for (int r = 0; r < 4; ++r) {
            float v = acc[nf][0][r] * inv[0] + acc[nf][1][r] * inv[1];
            #pragma unroll
            for (int o = 1; o <= 8; o <<= 1) v += __shfl_xor(v, o);
            cpl[nf][r] = v;
        }
    float* gslot = gavg + (size_t)(rb & (NSLOT - 1)) * NCOLS;
    if (l15 == 0) {
        #pragma unroll
        for (int nf = 0; nf < 5; ++nf)
            #pragma unroll
            for (int r = 0; r < 4; ++r)
                atomicAdd(&gslot[g * V_ + (tb + nf) * 16 + kq * 4 + r], cpl[nf][r]);
    }

    // ---- winner finalize + codevector gather: 64 (row,g) tasks, 8 threads each ----
    {
        const int task = t >> 3;             // 0..63
        const int seg  = t & 7;
        const int r_   = task >> 1, gg = task & 1;
        float best = s_bestv[gg][0][r_]; int bi = s_besti[gg][0][r_];
        #pragma unroll
        for (int q = 1; q < 4; ++q) {
            float v = s_bestv[gg][q][r_];
            if (v > best) { best = v; bi = s_besti[gg][q][r_]; }
        }
        const float* src = cv + ((size_t)gg * V_ + bi) * DCODE + seg * 16;
        float* dst = out + (size_t)(m0 + r_) * (G_ * DCODE) + gg * DCODE + seg * 16;
        #pragma unroll
        for (int j = 0; j < 4; ++j)
            stnt_f4(dst + j * 4, *(const f32x4*)(src + j * 4));
    }
}

// 1024-thr single block: phase1 threads<640 fold 64 slots, phase2 wave 0 reduces plogp.
__global__ __launch_bounds__(1024) void gvq_perp(const float* __restrict__ gavg,
                                                 float* __restrict__ out)
{
    __shared__ float sp[NCOLS];
    const int t = threadIdx.x;
    if (t < NCOLS) {
        float a = 0.f;
        #pragma unroll
        for (int sb = 0; sb < 8; ++sb) {
            float p[8];
            #pragma unroll
            for (int j = 0; j < 8; ++j)
                p[j] = gavg[(size_t)(sb * 8 + j) * NCOLS + t];
            #pragma unroll
            for (int j = 0; j < 8; ++j) a += p[j];
        }
        sp[t] = a;
    }
    __syncthreads();
    if (t < 64) {
        float s0 = 0.f, s1 = 0.f;
        #pragma unroll
        for (int j = 0; j < 5; ++j) {
            float p0 = sp[t + j * 64]      * (1.f / NROWS);
            float p1 = sp[V_ + t + j * 64] * (1.f / NROWS);
            s0 += p0 * __logf(p0 + 1e-7f);
            s1 += p1 * __logf(p1 + 1e-7f);
        }
        #pragma unroll
        for (int o = 1; o < 64; o <<= 1) {
            s0 += __shfl_xor(s0, o);
            s1 += __shfl_xor(s1, o);
        }
        if (t == 0)
            out[(size_t)NROWS * (G_ * DCODE)] = expf(-s0) + expf(-s1);
    }
}

extern "C" void kernel_launch(void* const* d_in, const int* in_sizes, int n_in,
                              void* d_out, int out_size, void* d_ws, size_t ws_size,
                              hipStream_t stream)
{
    const float* hidden = (const float*)d_in[0];
    const float* gu     = (const float*)d_in[1];
    const float* w      = (const float*)d_in[2];
    const float* b      = (const float*)d_in[3];
    const float* cv     = (const float*)d_in[4];
    float* out  = (float*)d_out;
    float* gavg = (float*)d_ws;                       // [NSLOT][640] f32 = 160 KB
    short* wpk  = (short*)((char*)d_ws + 163840);     // 640 KB fragment-packed W
    short* hpk  = (short*)((char*)d_ws + 819200);     // 33.5 MB fragment-packed H

    hipMemsetAsync(d_ws, 0, NSLOT * NCOLS * sizeof(float), stream);
    wprep<<<160, 256, 0, stream>>>(w, wpk);
    hprep<<<8192, 256, 0, stream>>>(hidden, hpk);
    gvq_gemm<<<NROWS / BMR, 512, 0, stream>>>(hpk, gu, wpk, b, cv, out, gavg);
    gvq_perp<<<1, 1024, 0, stream>>>(gavg, out);
}

// Round 22
// 106.972 us; speedup vs baseline: 1.2917x; 1.2917x over previous
//
#include <hip/hip_runtime.h>
#include <math.h>

#define NROWS 32768
#define CDIM  512
#define G_    2
#define V_    320
#define NCOLS 640
#define DCODE 128
#define NSLOT 64
#define BMR   32   // rows per block

typedef short bf16x8 __attribute__((ext_vector_type(8)));
typedef float f32x4  __attribute__((ext_vector_type(4)));

__device__ __forceinline__ short f2bf(float f) {
    union { float f; unsigned u; } v; v.f = f;
    unsigned r = v.u + 0x7FFFu + ((v.u >> 16) & 1u);   // RTNE
    return (short)(r >> 16);
}
__device__ __forceinline__ void gl_lds16(const void* g, void* l) {
    __builtin_amdgcn_global_load_lds(
        (const __attribute__((address_space(1))) unsigned int*)g,
        (__attribute__((address_space(3))) unsigned int*)l, 16, 0, 0);
}

// W [512][640] f32 -> wpk fragment-packed bf16 (640 KB).
// frag gid = ((g*16+ts)*20 + tt16)*64 + kq*16 + l15, elem e = w[ts*32+kq*8+e][g*320+tt16*16+l15]
__global__ __launch_bounds__(256) void wprep(const float* __restrict__ w,
                                             short* __restrict__ wpk) {
    int gid = blockIdx.x * 256 + threadIdx.x;       // 40960 fragments
    int l15 = gid & 15, kq = (gid >> 4) & 3;
    int rem = gid >> 6;
    int tt16 = rem % 20; rem /= 20;
    int ts = rem & 15, g = rem >> 4;
    int n  = g * V_ + tt16 * 16 + l15;
    int k0 = ts * 32 + kq * 8;
    bf16x8 o;
    #pragma unroll
    for (int e = 0; e < 8; ++e) o[e] = f2bf(w[(size_t)(k0 + e) * NCOLS + n]);
    *(bf16x8*)&wpk[(size_t)gid * 8] = o;
}

// hidden [32768][512] f32 -> hpk fragment-packed bf16 (33.5 MB).
// shorts index (rb,ts,mf,lane,e) = (((rb*16+ts)*2+mf)*64 + lane)*8 + e
//   = bf16(hidden[rb*32 + mf*16 + (lane&15)][ts*32 + (lane>>4)*8 + e])
__global__ __launch_bounds__(256) void hprep(const float* __restrict__ hidden,
                                             short* __restrict__ hpk) {
    int gid = blockIdx.x * 256 + threadIdx.x;       // 2,097,152
    int lane = gid & 63;
    int mf   = (gid >> 6) & 1;
    int ts   = (gid >> 7) & 15;
    int rb   = gid >> 11;
    int row  = rb * BMR + mf * 16 + (lane & 15);
    int k0   = ts * 32 + (lane >> 4) * 8;
    const float* src = hidden + (size_t)row * CDIM + k0;
    float4 a = *(const float4*)src;
    float4 b = *(const float4*)(src + 4);
    bf16x8 o;
    o[0]=f2bf(a.x); o[1]=f2bf(a.y); o[2]=f2bf(a.z); o[3]=f2bf(a.w);
    o[4]=f2bf(b.x); o[5]=f2bf(b.y); o[6]=f2bf(b.z); o[7]=f2bf(b.w);
    *(bf16x8*)&hpk[(size_t)gid * 8] = o;
}

// Block = 32 rows x 640 cols, 512 thr = 8 waves; wave cg owns cols cg*80..+80 (g=cg>>2).
// Swapped MFMA: D[n][m] = mfma(Wfrag, Hfrag).
// R21: H staged ONCE into LDS via global_load_lds (contiguous hpk slice, zero
// VGPR cost) -> the K-loop's vmem path carries ONLY the W stream (R16 ablation:
// W-alone ~3us; mixed W+H ~95-105us). H comes from conflict-free ds_read_b128.
__global__ __launch_bounds__(512, 3) void gvq_gemm(
    const short* __restrict__ hpk,       // fragment-packed bf16 hidden
    const float* __restrict__ gumbel_u,  // [65536][320] f32
    const short* __restrict__ wpk,       // fragment-packed bf16 W
    const float* __restrict__ bias,      // [640]
    const float* __restrict__ cv,        // [640][128]
    float* __restrict__ out,             // [32768][256] + perp scalar
    float* __restrict__ gavg)            // [NSLOT][640]
{
    __shared__ short Hs[16384];          // 32 KB: whole-K H slice of this block
    __shared__ float s_psum[G_][4][BMR];
    __shared__ float s_bestv[G_][4][BMR];
    __shared__ int   s_besti[G_][4][BMR];

    const int t    = threadIdx.x;
    const int wave = t >> 6;
    const int lane = t & 63;
    const int l15  = lane & 15;
    const int kq   = lane >> 4;
    const int cg   = wave;               // col group: 80 cols
    const int g    = cg >> 2;
    const int tb   = (cg & 3) * 5;       // tt16 base within group g
    const int rb   = blockIdx.x;
    const int m0   = rb * BMR;

    const short* wbase = wpk + ((size_t)(g * 16) * 20 + tb) * 512 + (size_t)lane * 8;

    // ---- prologue: stage block's 32 KB H slice via global_load_lds (4 x 1KB / wave) ----
    {
        const short* hsrc = hpk + (size_t)rb * 16384;
        #pragma unroll
        for (int i = 0; i < 4; ++i) {
            const int off = (wave * 4 + i) * 512;          // shorts
            gl_lds16(hsrc + off + lane * 8, &Hs[off]);
        }
    }

    f32x4 acc[5][2];                     // [nf][mf]
    #pragma unroll
    for (int nf = 0; nf < 5; ++nf)
        #pragma unroll
        for (int mf = 0; mf < 2; ++mf)
            #pragma unroll
            for (int r = 0; r < 4; ++r) acc[nf][mf][r] = 0.f;

    bf16x8 bw[5];
    #pragma unroll
    for (int nf = 0; nf < 5; ++nf) bw[nf] = *(const bf16x8*)(wbase + nf * 512);

    __syncthreads();                     // drains staging (compiler emits vmcnt(0))

    #pragma unroll
    for (int ts = 0; ts < 16; ++ts) {
        bf16x8 bn[5];
        if (ts < 15) {                   // prefetch W ts+1 (only vmem stream in loop)
            const short* wn = wbase + (ts + 1) * 10240;
            #pragma unroll
            for (int nf = 0; nf < 5; ++nf) bn[nf] = *(const bf16x8*)(wn + nf * 512);
        }
        bf16x8 hf0 = *(const bf16x8*)&Hs[ts * 1024 + lane * 8];
        bf16x8 hf1 = *(const bf16x8*)&Hs[ts * 1024 + 512 + lane * 8];
        #pragma unroll
        for (int nf = 0; nf < 5; ++nf)
            acc[nf][0] = __builtin_amdgcn_mfma_f32_16x16x32_bf16(bw[nf], hf0, acc[nf][0], 0, 0, 0);
        #pragma unroll
        for (int nf = 0; nf < 5; ++nf)
            acc[nf][1] = __builtin_amdgcn_mfma_f32_16x16x32_bf16(bw[nf], hf1, acc[nf][1], 0, 0, 0);
        #pragma unroll
        for (int nf = 0; nf < 5; ++nf) bw[nf] = bn[nf];
    }

    // ---- epilogue (lane owns rows m0+mf*16+l15, cols g*320+(tb+nf)*16+kq*4+r) ----
    float4 bv4[5], u4[2][5];
    #pragma unroll
    for (int nf = 0; nf < 5; ++nf)
        bv4[nf] = *(const float4*)&bias[g * V_ + (tb + nf) * 16 + kq * 4];
    #pragma unroll
    for (int mf = 0; mf < 2; ++mf) {
        const float* up = gumbel_u + ((size_t)(m0 + mf * 16 + l15) * G_ + g) * V_;
        #pragma unroll
        for (int nf = 0; nf < 5; ++nf)
            u4[mf][nf] = *(const float4*)&up[(tb + nf) * 16 + kq * 4];
    }

    #pragma unroll
    for (int mf = 0; mf < 2; ++mf) {
        float s = 0.f, best = -1e30f; int bi = 0;
        #pragma unroll
        for (int nf = 0; nf < 5; ++nf) {
            #pragma unroll
            for (int r = 0; r < 4; ++r) {
                float z = fminf(acc[nf][mf][r] + bv4[nf][r], 60.f);
                float e = __expf(z);
                acc[nf][mf][r] = e;                        // keep numerator for cp
                s += e;
                float u = (r == 0) ? u4[mf][nf].x : (r == 1) ? u4[mf][nf].y
                        : (r == 2) ? u4[mf][nf].z : u4[mf][nf].w;
                float wv = -__logf(u + 1e-10f) + 1e-10f;
                float ratio = e * __builtin_amdgcn_rcpf(wv);  // argmax(z+gumbel)==argmax e/wv
                const int vi = (tb + nf) * 16 + kq * 4 + r;   // ascending scan -> first-max
                if (ratio > best) { best = ratio; bi = vi; }
            }
        }
        // reduce across kq groups (cols): lanes l15, l15+16, l15+32, l15+48
        #pragma unroll
        for (int o = 16; o <= 32; o <<= 1) {
            s += __shfl_xor(s, o);
            float ov = __shfl_xor(best, o);
            int   oi = __shfl_xor(bi, o);
            if (ov > best || (ov == best && oi < bi)) { best = ov; bi = oi; }
        }
        if (kq == 0) {                       // lanes 0..15
            s_psum[g][cg & 3][mf * 16 + l15]  = s;
            s_bestv[g][cg & 3][mf * 16 + l15] = best;
            s_besti[g][cg & 3][mf * 16 + l15] = bi;
        }
    }
    __syncthreads();

    // ---- cp: per-lane e*inv summed over its 2 rows, fold l15, atomics (1 per col) ----
    float inv[2];
    #pragma unroll
    for (int mf = 0; mf < 2; ++mf) {
        const int rl = mf * 16 + l15;
        inv[mf] = 1.f / (s_psum[g][0][rl] + s_psum[g][1][rl] +
                         s_psum[g][2][rl] + s_psum[g][3][rl]);
    }
    float cpl[5][4];
    #pragma unroll
    for (int nf = 0; nf < 5; ++nf)
        #pragma unroll
        for (int r = 0; r < 4; ++r) {
            float v = acc[nf][0][r] * inv[0] + acc[nf][1][r] * inv[1];
            #pragma unroll
            for (int o = 1; o <= 8; o <<= 1) v += __shfl_xor(v, o);
            cpl[nf][r] = v;
        }
    float* gslot = gavg + (size_t)(rb & (NSLOT - 1)) * NCOLS;
    if (l15 == 0) {
        #pragma unroll
        for (int nf = 0; nf < 5; ++nf)
            #pragma unroll
            for (int r = 0; r < 4; ++r)
                atomicAdd(&gslot[g * V_ + (tb + nf) * 16 + kq * 4 + r], cpl[nf][r]);
    }

    // ---- winner finalize + codevector gather: 64 (row,g) tasks, 8 threads each ----
    {
        const int task = t >> 3;             // 0..63
        const int seg  = t & 7;
        const int r_   = task >> 1, gg = task & 1;
        float best = s_bestv[gg][0][r_]; int bi = s_besti[gg][0][r_];
        #pragma unroll
        for (int q = 1; q < 4; ++q) {
            float v = s_bestv[gg][q][r_];
            if (v > best) { best = v; bi = s_besti[gg][q][r_]; }
        }
        const float* src = cv + ((size_t)gg * V_ + bi) * DCODE + seg * 16;
        float* dst = out + (size_t)(m0 + r_) * (G_ * DCODE) + gg * DCODE + seg * 16;
        #pragma unroll
        for (int j = 0; j < 4; ++j)
            *(float4*)(dst + j * 4) = *(const float4*)(src + j * 4);
    }
}

// 1024-thr single block: phase1 threads<640 fold 64 slots, phase2 wave 0 reduces plogp.
__global__ __launch_bounds__(1024) void gvq_perp(const float* __restrict__ gavg,
                                                 float* __restrict__ out)
{
    __shared__ float sp[NCOLS];
    const int t = threadIdx.x;
    if (t < NCOLS) {
        float a = 0.f;
        #pragma unroll
        for (int sb = 0; sb < 8; ++sb) {
            float p[8];
            #pragma unroll
            for (int j = 0; j < 8; ++j)
                p[j] = gavg[(size_t)(sb * 8 + j) * NCOLS + t];
            #pragma unroll
            for (int j = 0; j < 8; ++j) a += p[j];
        }
        sp[t] = a;
    }
    __syncthreads();
    if (t < 64) {
        float s0 = 0.f, s1 = 0.f;
        #pragma unroll
        for (int j = 0; j < 5; ++j) {
            float p0 = sp[t + j * 64]      * (1.f / NROWS);
            float p1 = sp[V_ + t + j * 64] * (1.f / NROWS);
            s0 += p0 * __logf(p0 + 1e-7f);
            s1 += p1 * __logf(p1 + 1e-7f);
        }
        #pragma unroll
        for (int o = 1; o < 64; o <<= 1) {
            s0 += __shfl_xor(s0, o);
            s1 += __shfl_xor(s1, o);
        }
        if (t == 0)
            out[(size_t)NROWS * (G_ * DCODE)] = expf(-s0) + expf(-s1);
    }
}

extern "C" void kernel_launch(void* const* d_in, const int* in_sizes, int n_in,
                              void* d_out, int out_size, void* d_ws, size_t ws_size,
                              hipStream_t stream)
{
    const float* hidden = (const float*)d_in[0];
    const float* gu     = (const float*)d_in[1];
    const float* w      = (const float*)d_in[2];
    const float* b      = (const float*)d_in[3];
    const float* cv     = (const float*)d_in[4];
    float* out  = (float*)d_out;
    float* gavg = (float*)d_ws;                       // [NSLOT][640] f32 = 160 KB
    short* wpk  = (short*)((char*)d_ws + 163840);     // 640 KB fragment-packed W
    short* hpk  = (short*)((char*)d_ws + 819200);     // 33.5 MB fragment-packed H

    hipMemsetAsync(d_ws, 0, NSLOT * NCOLS * sizeof(float), stream);
    wprep<<<160, 256, 0, stream>>>(w, wpk);
    hprep<<<8192, 256, 0, stream>>>(hidden, hpk);
    gvq_gemm<<<NROWS / BMR, 512, 0, stream>>>(hpk, gu, wpk, b, cv, out, gavg);
    gvq_perp<<<1, 1024, 0, stream>>>(gavg, out);
}

// Round 23
// 97.189 us; speedup vs baseline: 1.4217x; 1.1007x over previous
//
#include <hip/hip_runtime.h>
#include <math.h>

#define NROWS 32768
#define CDIM  512
#define G_    2
#define V_    320
#define NCOLS 640
#define DCODE 128
#define NSLOT 64
#define BMR   32   // rows per block

typedef short bf16x8 __attribute__((ext_vector_type(8)));
typedef float f32x4  __attribute__((ext_vector_type(4)));

__device__ __forceinline__ short f2bf(float f) {
    union { float f; unsigned u; } v; v.f = f;
    unsigned r = v.u + 0x7FFFu + ((v.u >> 16) & 1u);   // RTNE
    return (short)(r >> 16);
}
__device__ __forceinline__ void gl_lds16(const void* g, void* l) {
    __builtin_amdgcn_global_load_lds(
        (const __attribute__((address_space(1))) unsigned int*)g,
        (__attribute__((address_space(3))) unsigned int*)l, 16, 0, 0);
}

// W [512][640] f32 -> wpk fragment-packed bf16 (640 KB).
// frag gid = ((g*16+ts)*20 + tt16)*64 + kq*16 + l15, elem e = w[ts*32+kq*8+e][g*320+tt16*16+l15]
__global__ __launch_bounds__(256) void wprep(const float* __restrict__ w,
                                             short* __restrict__ wpk) {
    int gid = blockIdx.x * 256 + threadIdx.x;       // 40960 fragments
    int l15 = gid & 15, kq = (gid >> 4) & 3;
    int rem = gid >> 6;
    int tt16 = rem % 20; rem /= 20;
    int ts = rem & 15, g = rem >> 4;
    int n  = g * V_ + tt16 * 16 + l15;
    int k0 = ts * 32 + kq * 8;
    bf16x8 o;
    #pragma unroll
    for (int e = 0; e < 8; ++e) o[e] = f2bf(w[(size_t)(k0 + e) * NCOLS + n]);
    *(bf16x8*)&wpk[(size_t)gid * 8] = o;
}

// hidden [32768][512] f32 -> hpk fragment-packed bf16 (33.5 MB).
// shorts index (rb,ts,mf,lane,e) = (((rb*16+ts)*2+mf)*64 + lane)*8 + e
//   = bf16(hidden[rb*32 + mf*16 + (lane&15)][ts*32 + (lane>>4)*8 + e])
__global__ __launch_bounds__(256) void hprep(const float* __restrict__ hidden,
                                             short* __restrict__ hpk) {
    int gid = blockIdx.x * 256 + threadIdx.x;       // 2,097,152
    int lane = gid & 63;
    int mf   = (gid >> 6) & 1;
    int ts   = (gid >> 7) & 15;
    int rb   = gid >> 11;
    int row  = rb * BMR + mf * 16 + (lane & 15);
    int k0   = ts * 32 + (lane >> 4) * 8;
    const float* src = hidden + (size_t)row * CDIM + k0;
    float4 a = *(const float4*)src;
    float4 b = *(const float4*)(src + 4);
    bf16x8 o;
    o[0]=f2bf(a.x); o[1]=f2bf(a.y); o[2]=f2bf(a.z); o[3]=f2bf(a.w);
    o[4]=f2bf(b.x); o[5]=f2bf(b.y); o[6]=f2bf(b.z); o[7]=f2bf(b.w);
    *(bf16x8*)&hpk[(size_t)gid * 8] = o;
}

// Block = 32 rows x ONE group (320 cols), 256 thr = 4 waves; wave ch owns 80 cols
// (tb = ch*5). Groups are independent softmax domains -> full fusion preserved.
// Smaller blocks double static blocks/CU (4 x 256thr = 16 waves/CU) to raise TLP,
// the lever the R21 post-mortem model (loads x 650cy / waves) identifies.
__global__ __launch_bounds__(256, 4) void gvq_gemm(
    const short* __restrict__ hpk,       // fragment-packed bf16 hidden
    const float* __restrict__ gumbel_u,  // [65536][320] f32
    const short* __restrict__ wpk,       // fragment-packed bf16 W
    const float* __restrict__ bias,      // [640]
    const float* __restrict__ cv,        // [640][128]
    float* __restrict__ out,             // [32768][256] + perp scalar
    float* __restrict__ gavg)            // [NSLOT][640]
{
    __shared__ short Hs[16384];          // 32 KB: whole-K H slice of this row-block
    __shared__ float s_psum[4][BMR];
    __shared__ float s_bestv[4][BMR];
    __shared__ int   s_besti[4][BMR];

    const int t    = threadIdx.x;
    const int wave = t >> 6;             // = ch: col quarter of the group
    const int lane = t & 63;
    const int l15  = lane & 15;
    const int kq   = lane >> 4;
    const int tb   = wave * 5;           // tt16 base within group
    const int rb   = blockIdx.x;
    const int g    = blockIdx.y;
    const int m0   = rb * BMR;

    const short* wbase = wpk + ((size_t)(g * 16) * 20 + tb) * 512 + (size_t)lane * 8;

    // ---- prologue: stage block's 32 KB H slice via global_load_lds (8 x 1KB / wave) ----
    {
        const short* hsrc = hpk + (size_t)rb * 16384;
        #pragma unroll
        for (int i = 0; i < 8; ++i) {
            const int off = (wave * 8 + i) * 512;          // shorts
            gl_lds16(hsrc + off + lane * 8, &Hs[off]);
        }
    }

    f32x4 acc[5][2];                     // [nf][mf]
    #pragma unroll
    for (int nf = 0; nf < 5; ++nf)
        #pragma unroll
        for (int mf = 0; mf < 2; ++mf)
            #pragma unroll
            for (int r = 0; r < 4; ++r) acc[nf][mf][r] = 0.f;

    bf16x8 bw[5];
    #pragma unroll
    for (int nf = 0; nf < 5; ++nf) bw[nf] = *(const bf16x8*)(wbase + nf * 512);

    __syncthreads();                     // drains staging

    #pragma unroll
    for (int ts = 0; ts < 16; ++ts) {
        bf16x8 bn[5];
        if (ts < 15) {                   // prefetch W ts+1 (only vmem stream in loop)
            const short* wn = wbase + (ts + 1) * 10240;
            #pragma unroll
            for (int nf = 0; nf < 5; ++nf) bn[nf] = *(const bf16x8*)(wn + nf * 512);
        }
        bf16x8 hf0 = *(const bf16x8*)&Hs[ts * 1024 + lane * 8];
        bf16x8 hf1 = *(const bf16x8*)&Hs[ts * 1024 + 512 + lane * 8];
        #pragma unroll
        for (int nf = 0; nf < 5; ++nf)
            acc[nf][0] = __builtin_amdgcn_mfma_f32_16x16x32_bf16(bw[nf], hf0, acc[nf][0], 0, 0, 0);
        #pragma unroll
        for (int nf = 0; nf < 5; ++nf)
            acc[nf][1] = __builtin_amdgcn_mfma_f32_16x16x32_bf16(bw[nf], hf1, acc[nf][1], 0, 0, 0);
        #pragma unroll
        for (int nf = 0; nf < 5; ++nf) bw[nf] = bn[nf];
    }

    // ---- epilogue (lane owns rows m0+mf*16+l15, cols g*320+(tb+nf)*16+kq*4+r) ----
    float4 bv4[5], u4[2][5];
    #pragma unroll
    for (int nf = 0; nf < 5; ++nf)
        bv4[nf] = *(const float4*)&bias[g * V_ + (tb + nf) * 16 + kq * 4];
    #pragma unroll
    for (int mf = 0; mf < 2; ++mf) {
        const float* up = gumbel_u + ((size_t)(m0 + mf * 16 + l15) * G_ + g) * V_;
        #pragma unroll
        for (int nf = 0; nf < 5; ++nf)
            u4[mf][nf] = *(const float4*)&up[(tb + nf) * 16 + kq * 4];
    }

    #pragma unroll
    for (int mf = 0; mf < 2; ++mf) {
        float s = 0.f, best = -1e30f; int bi = 0;
        #pragma unroll
        for (int nf = 0; nf < 5; ++nf) {
            #pragma unroll
            for (int r = 0; r < 4; ++r) {
                float z = fminf(acc[nf][mf][r] + bv4[nf][r], 60.f);
                float e = __expf(z);
                acc[nf][mf][r] = e;                        // keep numerator for cp
                s += e;
                float u = (r == 0) ? u4[mf][nf].x : (r == 1) ? u4[mf][nf].y
                        : (r == 2) ? u4[mf][nf].z : u4[mf][nf].w;
                float wv = -__logf(u + 1e-10f) + 1e-10f;
                float ratio = e * __builtin_amdgcn_rcpf(wv);  // argmax(z+gumbel)==argmax e/wv
                const int vi = (tb + nf) * 16 + kq * 4 + r;   // ascending scan -> first-max
                if (ratio > best) { best = ratio; bi = vi; }
            }
        }
        // reduce across kq groups (cols): lanes l15, l15+16, l15+32, l15+48
        #pragma unroll
        for (int o = 16; o <= 32; o <<= 1) {
            s += __shfl_xor(s, o);
            float ov = __shfl_xor(best, o);
            int   oi = __shfl_xor(bi, o);
            if (ov > best || (ov == best && oi < bi)) { best = ov; bi = oi; }
        }
        if (kq == 0) {                       // lanes 0..15
            s_psum[wave][mf * 16 + l15]  = s;
            s_bestv[wave][mf * 16 + l15] = best;
            s_besti[wave][mf * 16 + l15] = bi;
        }
    }
    __syncthreads();

    // ---- cp: per-lane e*inv summed over its 2 rows, fold l15, atomics (1 per col) ----
    float inv[2];
    #pragma unroll
    for (int mf = 0; mf < 2; ++mf) {
        const int rl = mf * 16 + l15;
        inv[mf] = 1.f / (s_psum[0][rl] + s_psum[1][rl] +
                         s_psum[2][rl] + s_psum[3][rl]);
    }
    float cpl[5][4];
    #pragma unroll
    for (int nf = 0; nf < 5; ++nf)
        #pragma unroll
        for (int r = 0; r < 4; ++r) {
            float v = acc[nf][0][r] * inv[0] + acc[nf][1][r] * inv[1];
            #pragma unroll
            for (int o = 1; o <= 8; o <<= 1) v += __shfl_xor(v, o);
            cpl[nf][r] = v;
        }
    float* gslot = gavg + (size_t)(rb & (NSLOT - 1)) * NCOLS;
    if (l15 == 0) {
        #pragma unroll
        for (int nf = 0; nf < 5; ++nf)
            #pragma unroll
            for (int r = 0; r < 4; ++r)
                atomicAdd(&gslot[g * V_ + (tb + nf) * 16 + kq * 4 + r], cpl[nf][r]);
    }

    // ---- winner finalize + codevector gather: 32 row tasks, 8 threads each ----
    {
        const int r_  = t >> 3;              // 0..31
        const int seg = t & 7;
        float best = s_bestv[0][r_]; int bi = s_besti[0][r_];
        #pragma unroll
        for (int q = 1; q < 4; ++q) {
            float v = s_bestv[q][r_];
            if (v > best) { best = v; bi = s_besti[q][r_]; }   // ascending ch => first-max
        }
        const float* src = cv + ((size_t)g * V_ + bi) * DCODE + seg * 16;
        float* dst = out + (size_t)(m0 + r_) * (G_ * DCODE) + g * DCODE + seg * 16;
        #pragma unroll
        for (int j = 0; j < 4; ++j)
            *(float4*)(dst + j * 4) = *(const float4*)(src + j * 4);
    }
}

// 1024-thr single block: phase1 threads<640 fold 64 slots, phase2 wave 0 reduces plogp.
__global__ __launch_bounds__(1024) void gvq_perp(const float* __restrict__ gavg,
                                                 float* __restrict__ out)
{
    __shared__ float sp[NCOLS];
    const int t = threadIdx.x;
    if (t < NCOLS) {
        float a = 0.f;
        #pragma unroll
        for (int sb = 0; sb < 8; ++sb) {
            float p[8];
            #pragma unroll
            for (int j = 0; j < 8; ++j)
                p[j] = gavg[(size_t)(sb * 8 + j) * NCOLS + t];
            #pragma unroll
            for (int j = 0; j < 8; ++j) a += p[j];
        }
        sp[t] = a;
    }
    __syncthreads();
    if (t < 64) {
        float s0 = 0.f, s1 = 0.f;
        #pragma unroll
        for (int j = 0; j < 5; ++j) {
            float p0 = sp[t + j * 64]      * (1.f / NROWS);
            float p1 = sp[V_ + t + j * 64] * (1.f / NROWS);
            s0 += p0 * __logf(p0 + 1e-7f);
            s1 += p1 * __logf(p1 + 1e-7f);
        }
        #pragma unroll
        for (int o = 1; o < 64; o <<= 1) {
            s0 += __shfl_xor(s0, o);
            s1 += __shfl_xor(s1, o);
        }
        if (t == 0)
            out[(size_t)NROWS * (G_ * DCODE)] = expf(-s0) + expf(-s1);
    }
}

extern "C" void kernel_launch(void* const* d_in, const int* in_sizes, int n_in,
                              void* d_out, int out_size, void* d_ws, size_t ws_size,
                              hipStream_t stream)
{
    const float* hidden = (const float*)d_in[0];
    const float* gu     = (const float*)d_in[1];
    const float* w      = (const float*)d_in[2];
    const float* b      = (const float*)d_in[3];
    const float* cv     = (const float*)d_in[4];
    float* out  = (float*)d_out;
    float* gavg = (float*)d_ws;                       // [NSLOT][640] f32 = 160 KB
    short* wpk  = (short*)((char*)d_ws + 163840);     // 640 KB fragment-packed W
    short* hpk  = (short*)((char*)d_ws + 819200);     // 33.5 MB fragment-packed H

    hipMemsetAsync(d_ws, 0, NSLOT * NCOLS * sizeof(float), stream);
    wprep<<<160, 256, 0, stream>>>(w, wpk);
    hprep<<<8192, 256, 0, stream>>>(hidden, hpk);
    gvq_gemm<<<dim3(NROWS / BMR, G_), 256, 0, stream>>>(hpk, gu, wpk, b, cv, out, gavg);
    gvq_perp<<<1, 1024, 0, stream>>>(gavg, out);
}

// Round 24
// 86.813 us; speedup vs baseline: 1.5916x; 1.1195x over previous
//
#include <hip/hip_runtime.h>
#include <math.h>

#define NROWS 32768
#define CDIM  512
#define G_    2
#define V_    320
#define NCOLS 640
#define DCODE 128
#define NSLOT 64
#define BMR   32   // rows per block

typedef short bf16x8 __attribute__((ext_vector_type(8)));
typedef float f32x4  __attribute__((ext_vector_type(4)));

__device__ __forceinline__ short f2bf(float f) {
    union { float f; unsigned u; } v; v.f = f;
    unsigned r = v.u + 0x7FFFu + ((v.u >> 16) & 1u);   // RTNE
    return (short)(r >> 16);
}
__device__ __forceinline__ void gl_lds16(const void* g, void* l) {
    __builtin_amdgcn_global_load_lds(
        (const __attribute__((address_space(1))) unsigned int*)g,
        (__attribute__((address_space(3))) unsigned int*)l, 16, 0, 0);
}

// W [512][640] f32 -> wpk fragment-packed bf16 (640 KB).
// frag gid = ((g*16+ts)*20 + tt16)*64 + kq*16 + l15, elem e = w[ts*32+kq*8+e][g*320+tt16*16+l15]
__global__ __launch_bounds__(256) void wprep(const float* __restrict__ w,
                                             short* __restrict__ wpk) {
    int gid = blockIdx.x * 256 + threadIdx.x;       // 40960 fragments
    int l15 = gid & 15, kq = (gid >> 4) & 3;
    int rem = gid >> 6;
    int tt16 = rem % 20; rem /= 20;
    int ts = rem & 15, g = rem >> 4;
    int n  = g * V_ + tt16 * 16 + l15;
    int k0 = ts * 32 + kq * 8;
    bf16x8 o;
    #pragma unroll
    for (int e = 0; e < 8; ++e) o[e] = f2bf(w[(size_t)(k0 + e) * NCOLS + n]);
    *(bf16x8*)&wpk[(size_t)gid * 8] = o;
}

// hidden [32768][512] f32 -> hpk fragment-packed bf16 (33.5 MB).
// shorts index (rb,ts,mf,lane,e) = (((rb*16+ts)*2+mf)*64 + lane)*8 + e
//   = bf16(hidden[rb*32 + mf*16 + (lane&15)][ts*32 + (lane>>4)*8 + e])
__global__ __launch_bounds__(256) void hprep(const float* __restrict__ hidden,
                                             short* __restrict__ hpk) {
    int gid = blockIdx.x * 256 + threadIdx.x;       // 2,097,152
    int lane = gid & 63;
    int mf   = (gid >> 6) & 1;
    int ts   = (gid >> 7) & 15;
    int rb   = gid >> 11;
    int row  = rb * BMR + mf * 16 + (lane & 15);
    int k0   = ts * 32 + (lane >> 4) * 8;
    const float* src = hidden + (size_t)row * CDIM + k0;
    float4 a = *(const float4*)src;
    float4 b = *(const float4*)(src + 4);
    bf16x8 o;
    o[0]=f2bf(a.x); o[1]=f2bf(a.y); o[2]=f2bf(a.z); o[3]=f2bf(a.w);
    o[4]=f2bf(b.x); o[5]=f2bf(b.y); o[6]=f2bf(b.z); o[7]=f2bf(b.w);
    *(bf16x8*)&hpk[(size_t)gid * 8] = o;
}

// Block = 32 rows x ONE group (320 cols), 256 thr = 4 waves; wave ch owns 80 cols.
// R23: launch_bounds(256,2) raises the VGPR cap to ~256 (LDS caps occupancy at
// 4 blocks/CU = 16 waves regardless, needing only VGPR<=128) so the compiler
// has no occupancy incentive to serialize the W pipeline (R12-R22: VGPR stuck
// 52-88 = buffers destroyed). W prefetch deepened to 2-ahead (3 live slots).
__global__ __launch_bounds__(256, 2) void gvq_gemm(
    const short* __restrict__ hpk,       // fragment-packed bf16 hidden
    const float* __restrict__ gumbel_u,  // [65536][320] f32
    const short* __restrict__ wpk,       // fragment-packed bf16 W
    const float* __restrict__ bias,      // [640]
    const float* __restrict__ cv,        // [640][128]
    float* __restrict__ out,             // [32768][256] + perp scalar
    float* __restrict__ gavg)            // [NSLOT][640]
{
    __shared__ short Hs[16384];          // 32 KB: whole-K H slice of this row-block
    __shared__ float s_psum[4][BMR];
    __shared__ float s_bestv[4][BMR];
    __shared__ int   s_besti[4][BMR];

    const int t    = threadIdx.x;
    const int wave = t >> 6;             // = ch: col quarter of the group
    const int lane = t & 63;
    const int l15  = lane & 15;
    const int kq   = lane >> 4;
    const int tb   = wave * 5;           // tt16 base within group
    const int rb   = blockIdx.x;
    const int g    = blockIdx.y;
    const int m0   = rb * BMR;

    const short* wbase = wpk + ((size_t)(g * 16) * 20 + tb) * 512 + (size_t)lane * 8;

    // ---- prologue: stage block's 32 KB H slice via global_load_lds (8 x 1KB / wave) ----
    {
        const short* hsrc = hpk + (size_t)rb * 16384;
        #pragma unroll
        for (int i = 0; i < 8; ++i) {
            const int off = (wave * 8 + i) * 512;          // shorts
            gl_lds16(hsrc + off + lane * 8, &Hs[off]);
        }
    }

    f32x4 acc[5][2];                     // [nf][mf]
    #pragma unroll
    for (int nf = 0; nf < 5; ++nf)
        #pragma unroll
        for (int mf = 0; mf < 2; ++mf)
            #pragma unroll
            for (int r = 0; r < 4; ++r) acc[nf][mf][r] = 0.f;

    // 3-slot W pipeline: preload ts=0, ts=1
    bf16x8 bw[5], bn[5];
    #pragma unroll
    for (int nf = 0; nf < 5; ++nf) bw[nf] = *(const bf16x8*)(wbase + nf * 512);
    #pragma unroll
    for (int nf = 0; nf < 5; ++nf) bn[nf] = *(const bf16x8*)(wbase + 10240 + nf * 512);

    __syncthreads();                     // drains staging

    #pragma unroll
    for (int ts = 0; ts < 16; ++ts) {
        bf16x8 b2[5];
        if (ts < 14) {                   // issue W ts+2 (2-deep pipeline)
            const short* wn = wbase + (ts + 2) * 10240;
            #pragma unroll
            for (int nf = 0; nf < 5; ++nf) b2[nf] = *(const bf16x8*)(wn + nf * 512);
        }
        bf16x8 hf0 = *(const bf16x8*)&Hs[ts * 1024 + lane * 8];
        bf16x8 hf1 = *(const bf16x8*)&Hs[ts * 1024 + 512 + lane * 8];
        #pragma unroll
        for (int nf = 0; nf < 5; ++nf)
            acc[nf][0] = __builtin_amdgcn_mfma_f32_16x16x32_bf16(bw[nf], hf0, acc[nf][0], 0, 0, 0);
        #pragma unroll
        for (int nf = 0; nf < 5; ++nf)
            acc[nf][1] = __builtin_amdgcn_mfma_f32_16x16x32_bf16(bw[nf], hf1, acc[nf][1], 0, 0, 0);
        #pragma unroll
        for (int nf = 0; nf < 5; ++nf) { bw[nf] = bn[nf]; bn[nf] = b2[nf]; }
    }

    // ---- epilogue (lane owns rows m0+mf*16+l15, cols g*320+(tb+nf)*16+kq*4+r) ----
    float4 bv4[5], u4[2][5];
    #pragma unroll
    for (int nf = 0; nf < 5; ++nf)
        bv4[nf] = *(const float4*)&bias[g * V_ + (tb + nf) * 16 + kq * 4];
    #pragma unroll
    for (int mf = 0; mf < 2; ++mf) {
        const float* up = gumbel_u + ((size_t)(m0 + mf * 16 + l15) * G_ + g) * V_;
        #pragma unroll
        for (int nf = 0; nf < 5; ++nf)
            u4[mf][nf] = *(const float4*)&up[(tb + nf) * 16 + kq * 4];
    }

    #pragma unroll
    for (int mf = 0; mf < 2; ++mf) {
        float s = 0.f, best = -1e30f; int bi = 0;
        #pragma unroll
        for (int nf = 0; nf < 5; ++nf) {
            #pragma unroll
            for (int r = 0; r < 4; ++r) {
                float z = fminf(acc[nf][mf][r] + bv4[nf][r], 60.f);
                float e = __expf(z);
                acc[nf][mf][r] = e;                        // keep numerator for cp
                s += e;
                float u = (r == 0) ? u4[mf][nf].x : (r == 1) ? u4[mf][nf].y
                        : (r == 2) ? u4[mf][nf].z : u4[mf][nf].w;
                float wv = -__logf(u + 1e-10f) + 1e-10f;
                float ratio = e * __builtin_amdgcn_rcpf(wv);  // argmax(z+gumbel)==argmax e/wv
                const int vi = (tb + nf) * 16 + kq * 4 + r;   // ascending scan -> first-max
                if (ratio > best) { best = ratio; bi = vi; }
            }
        }
        // reduce across kq groups (cols): lanes l15, l15+16, l15+32, l15+48
        #pragma unroll
        for (int o = 16; o <= 32; o <<= 1) {
            s += __shfl_xor(s, o);
            float ov = __shfl_xor(best, o);
            int   oi = __shfl_xor(bi, o);
            if (ov > best || (ov == best && oi < bi)) { best = ov; bi = oi; }
        }
        if (kq == 0) {                       // lanes 0..15
            s_psum[wave][mf * 16 + l15]  = s;
            s_bestv[wave][mf * 16 + l15] = best;
            s_besti[wave][mf * 16 + l15] = bi;
        }
    }
    __syncthreads();

    // ---- cp: per-lane e*inv summed over its 2 rows, fold l15, atomics (1 per col) ----
    float inv[2];
    #pragma unroll
    for (int mf = 0; mf < 2; ++mf) {
        const int rl = mf * 16 + l15;
        inv[mf] = 1.f / (s_psum[0][rl] + s_psum[1][rl] +
                         s_psum[2][rl] + s_psum[3][rl]);
    }
    float cpl[5][4];
    #pragma unroll
    for (int nf = 0; nf < 5; ++nf)
        #pragma unroll
        for (int r = 0; r < 4; ++r) {
            float v = acc[nf][0][r] * inv[0] + acc[nf][1][r] * inv[1];
            #pragma unroll
            for (int o = 1; o <= 8; o <<= 1) v += __shfl_xor(v, o);
            cpl[nf][r] = v;
        }
    float* gslot = gavg + (size_t)(rb & (NSLOT - 1)) * NCOLS;
    if (l15 == 0) {
        #pragma unroll
        for (int nf = 0; nf < 5; ++nf)
            #pragma unroll
            for (int r = 0; r < 4; ++r)
                atomicAdd(&gslot[g * V_ + (tb + nf) * 16 + kq * 4 + r], cpl[nf][r]);
    }

    // ---- winner finalize + codevector gather: 32 row tasks, 8 threads each ----
    {
        const int r_  = t >> 3;              // 0..31
        const int seg = t & 7;
        float best = s_bestv[0][r_]; int bi = s_besti[0][r_];
        #pragma unroll
        for (int q = 1; q < 4; ++q) {
            float v = s_bestv[q][r_];
            if (v > best) { best = v; bi = s_besti[q][r_]; }   // ascending ch => first-max
        }
        const float* src = cv + ((size_t)g * V_ + bi) * DCODE + seg * 16;
        float* dst = out + (size_t)(m0 + r_) * (G_ * DCODE) + g * DCODE + seg * 16;
        #pragma unroll
        for (int j = 0; j < 4; ++j)
            *(float4*)(dst + j * 4) = *(const float4*)(src + j * 4);
    }
}

// 1024-thr single block: phase1 threads<640 fold 64 slots, phase2 wave 0 reduces plogp.
__global__ __launch_bounds__(1024) void gvq_perp(const float* __restrict__ gavg,
                                                 float* __restrict__ out)
{
    __shared__ float sp[NCOLS];
    const int t = threadIdx.x;
    if (t < NCOLS) {
        float a = 0.f;
        #pragma unroll
        for (int sb = 0; sb < 8; ++sb) {
            float p[8];
            #pragma unroll
            for (int j = 0; j < 8; ++j)
                p[j] = gavg[(size_t)(sb * 8 + j) * NCOLS + t];
            #pragma unroll
            for (int j = 0; j < 8; ++j) a += p[j];
        }
        sp[t] = a;
    }
    __syncthreads();
    if (t < 64) {
        float s0 = 0.f, s1 = 0.f;
        #pragma unroll
        for (int j = 0; j < 5; ++j) {
            float p0 = sp[t + j * 64]      * (1.f / NROWS);
            float p1 = sp[V_ + t + j * 64] * (1.f / NROWS);
            s0 += p0 * __logf(p0 + 1e-7f);
            s1 += p1 * __logf(p1 + 1e-7f);
        }
        #pragma unroll
        for (int o = 1; o < 64; o <<= 1) {
            s0 += __shfl_xor(s0, o);
            s1 += __shfl_xor(s1, o);
        }
        if (t == 0)
            out[(size_t)NROWS * (G_ * DCODE)] = expf(-s0) + expf(-s1);
    }
}

extern "C" void kernel_launch(void* const* d_in, const int* in_sizes, int n_in,
                              void* d_out, int out_size, void* d_ws, size_t ws_size,
                              hipStream_t stream)
{
    const float* hidden = (const float*)d_in[0];
    const float* gu     = (const float*)d_in[1];
    const float* w      = (const float*)d_in[2];
    const float* b      = (const float*)d_in[3];
    const float* cv     = (const float*)d_in[4];
    float* out  = (float*)d_out;
    float* gavg = (float*)d_ws;                       // [NSLOT][640] f32 = 160 KB
    short* wpk  = (short*)((char*)d_ws + 163840);     // 640 KB fragment-packed W
    short* hpk  = (short*)((char*)d_ws + 819200);     // 33.5 MB fragment-packed H

    hipMemsetAsync(d_ws, 0, NSLOT * NCOLS * sizeof(float), stream);
    wprep<<<160, 256, 0, stream>>>(w, wpk);
    hprep<<<8192, 256, 0, stream>>>(hidden, hpk);
    gvq_gemm<<<dim3(NROWS / BMR, G_), 256, 0, stream>>>(hpk, gu, wpk, b, cv, out, gavg);
    gvq_perp<<<1, 1024, 0, stream>>>(gavg, out);
}